// Round 3
// baseline (141.638 us; speedup 1.0000x reference)
//
#include <hip/hip_runtime.h>

// Chamfer distance: B=4, S=4, N=M=4096, D=3, fp32 in/out.
// out[s*B + b] = mean_n min_m d2(n,m) + mean_m min_n d2(n,m)
//
// R2: refs are wave-uniform -> stream them through SGPRs (s_load_dwordx16),
// not LDS. R1 was DS-pipe writeback bound (broadcast ds_read_b128 = 1024 B
// VGPR writeback per wave per ref -> 109 us model ~= 92.6 us measured).
// Inner loop: t = y2/2 - x.y  ->  mul(1sgpr) + 2 fma(1sgpr) + sub(sgpr src0)
// + min = 5 VALU ops/pair, zero DS traffic. d2 = max(x2 + 2*min t, 0).
// R3 fix: half-index laundered through readfirstlane so the ref pointer is
// compiler-uniform (R2 put the s_load address in VGPRs -> compile error).

constexpr int B = 4, S = 4, NPTS = 4096, PAIRS = B * S;
constexpr int THREADS = 256;
constexpr int QPB = 128;                  // queries per block (2 ref-halves)
constexpr int HALF = NPTS / 2;            // refs per half-stream
constexpr int QTILES = NPTS / QPB;        // 32
constexpr size_t WS_ELEMS = (size_t)2 * PAIRS * NPTS;          // packed float4 refs
constexpr size_t WS_NEED  = WS_ELEMS * sizeof(float4) + 256;   // +prefetch overshoot pad

typedef float v16f __attribute__((ext_vector_type(16)));

#define SLOAD(dst, p, imm) \
  asm volatile("s_load_dwordx16 %0, %1, %2" : "=s"(dst) : "s"(p), "i"(imm))
#define SWAIT2(a, b) \
  asm volatile("s_waitcnt lgkmcnt(0)" : "+s"(a), "+s"(b))

// ---- prep: pack refs as (x, y, z, 0.5*|r|^2), layout [dir][pair][n] ----
__global__ void prep_kernel(const float* __restrict__ out_pts,
                            const float* __restrict__ tgt_pts,
                            float4* __restrict__ ws) {
  int i = blockIdx.x * blockDim.x + threadIdx.x;   // 0 .. 2*16*4096-1
  int dir = i >> 16;                                // 16*4096 = 65536 per dir
  int rem = i & 65535;                              // pair*NPTS + n
  const float* p = (dir == 0 ? tgt_pts : out_pts) + (size_t)rem * 3;
  float x = p[0], y = p[1], z = p[2];
  ws[i] = make_float4(x, y, z, 0.5f * (x * x + y * y + z * z));
}

// ---- main: SGPR-streamed brute-force NN ----
__global__ __launch_bounds__(THREADS, 4)
void chamfer_sgpr_kernel(const float* __restrict__ out_pts,
                         const float* __restrict__ tgt_pts,
                         const float4* __restrict__ ws,
                         float* __restrict__ out) {
  const int t     = threadIdx.x;
  const int qtile = blockIdx.x;   // 0..31
  const int pair  = blockIdx.y;   // 0..15  (pair = b*S + s)
  const int dir   = blockIdx.z;   // 0: out->tgt, 1: tgt->out
  // Wave-uniform half index, laundered through readfirstlane so the ref
  // pointer chain stays in SGPRs (waves 0,1 -> half 0; waves 2,3 -> half 1).
  const int half  = __builtin_amdgcn_readfirstlane(t) >> 7;

  const float* qbase = (dir == 0 ? out_pts : tgt_pts) + (size_t)pair * NPTS * 3;
  const float4* rbase =
      ws + (size_t)(dir * PAIRS + pair) * NPTS + (size_t)half * HALF;

  const int q = qtile * QPB + (t & 127);
  const float qx = qbase[q * 3 + 0];
  const float qy = qbase[q * 3 + 1];
  const float qz = qbase[q * 3 + 2];

  float mm[8];
  #pragma unroll
  for (int u = 0; u < 8; ++u) mm[u] = 3.0e38f;

  // Double-buffered SMEM stream: 8 refs (128 B = 2x s_load_dwordx16) per batch.
  // SMEM may complete out of order -> every wait is a full lgkmcnt(0) drain,
  // so each batch's loads are issued BEFORE the drain that precedes its use.
  v16f a0, a1, b0, b1;
  const float4* p = rbase;
  SLOAD(a0, p, 0);  SLOAD(a1, p, 64);

  #define BODY8(va, vb)                                         \
    { _Pragma("unroll") for (int j = 0; j < 4; ++j) {           \
        float dx = qx * (va)[4 * j];                            \
        dx = fmaf(qy, (va)[4 * j + 1], dx);                     \
        dx = fmaf(qz, (va)[4 * j + 2], dx);                     \
        mm[j] = fminf(mm[j], (va)[4 * j + 3] - dx); }           \
      _Pragma("unroll") for (int j = 0; j < 4; ++j) {           \
        float dx = qx * (vb)[4 * j];                            \
        dx = fmaf(qy, (vb)[4 * j + 1], dx);                     \
        dx = fmaf(qz, (vb)[4 * j + 2], dx);                     \
        mm[4 + j] = fminf(mm[4 + j], (vb)[4 * j + 3] - dx); } }

  for (int k = 0; k < HALF; k += 16) {
    SWAIT2(a0, a1);
    SLOAD(b0, p, 128); SLOAD(b1, p, 192);   // batch k+8 in flight
    BODY8(a0, a1);                          // batch k
    SWAIT2(b0, b1);
    SLOAD(a0, p, 256); SLOAD(a1, p, 320);   // batch k+16 in flight (overshoots
    BODY8(b0, b1);                          //  <=384 B past end; ws is padded)
    p += 16;
  }
  #undef BODY8

  float tmin = fminf(fminf(fminf(mm[0], mm[1]), fminf(mm[2], mm[3])),
                     fminf(fminf(mm[4], mm[5]), fminf(mm[6], mm[7])));
  const float x2 = qx * qx + qy * qy + qz * qz;

  __shared__ float smin[QPB];
  __shared__ float red[2];
  if (t >= 128) smin[t - 128] = tmin;       // half 1 -> LDS
  __syncthreads();
  if (t < 128) {
    tmin = fminf(tmin, smin[t]);
    float d = fmaxf(fmaf(2.0f, tmin, x2), 0.0f);
    #pragma unroll
    for (int off = 1; off < 64; off <<= 1) d += __shfl_xor(d, off, 64);
    if ((t & 63) == 0) red[t >> 6] = d;
  }
  __syncthreads();
  if (t == 0) {
    float ssum = red[0] + red[1];
    int b = pair >> 2, s = pair & 3;        // pair = b*S + s, S = 4
    atomicAdd(&out[s * B + b], ssum * (1.0f / NPTS));
  }
}

// ---- R1 fallback (LDS broadcast) in case d_ws is too small ----
constexpr int FB_CHUNK = 2048;
__global__ __launch_bounds__(THREADS, 2)
void chamfer_lds_kernel(const float* __restrict__ out_pts,
                        const float* __restrict__ tgt_pts,
                        float* __restrict__ out) {
  const int t = threadIdx.x, qtile = blockIdx.x, pair = blockIdx.y, dir = blockIdx.z;
  const float* qbase = (dir == 0 ? out_pts : tgt_pts) + (size_t)pair * NPTS * 3;
  const float* rbase = (dir == 0 ? tgt_pts : out_pts) + (size_t)pair * NPTS * 3;
  __shared__ float4 sref[FB_CHUNK];
  const int q = qtile * THREADS + t;
  const float qx = qbase[q * 3], qy = qbase[q * 3 + 1], qz = qbase[q * 3 + 2];
  float mm[8];
  #pragma unroll
  for (int u = 0; u < 8; ++u) mm[u] = 3.0e38f;
  for (int c0 = 0; c0 < NPTS; c0 += FB_CHUNK) {
    if (c0) __syncthreads();
    for (int i = t; i < FB_CHUNK; i += THREADS) {
      const float* p = rbase + (size_t)(c0 + i) * 3;
      float rx = p[0], ry = p[1], rz = p[2];
      sref[i] = make_float4(rx, ry, rz, 0.5f * (rx * rx + ry * ry + rz * rz));
    }
    __syncthreads();
    for (int k = 0; k < FB_CHUNK; k += 8) {
      #pragma unroll
      for (int u = 0; u < 8; ++u) {
        float4 r = sref[k + u];
        float a = fmaf(-qx, r.x, r.w);
        a = fmaf(-qy, r.y, a);
        a = fmaf(-qz, r.z, a);
        mm[u] = fminf(mm[u], a);
      }
    }
  }
  float tmin = fminf(fminf(fminf(mm[0], mm[1]), fminf(mm[2], mm[3])),
                     fminf(fminf(mm[4], mm[5]), fminf(mm[6], mm[7])));
  float x2 = qx * qx + qy * qy + qz * qz;
  float d = fmaxf(fmaf(2.0f, tmin, x2), 0.0f);
  #pragma unroll
  for (int off = 1; off < 64; off <<= 1) d += __shfl_xor(d, off, 64);
  __syncthreads();
  float* red = reinterpret_cast<float*>(sref);
  if ((t & 63) == 0) red[t >> 6] = d;
  __syncthreads();
  if (t == 0) {
    float ssum = red[0] + red[1] + red[2] + red[3];
    int b = pair >> 2, s = pair & 3;
    atomicAdd(&out[s * B + b], ssum * (1.0f / NPTS));
  }
}

extern "C" void kernel_launch(void* const* d_in, const int* in_sizes, int n_in,
                              void* d_out, int out_size, void* d_ws, size_t ws_size,
                              hipStream_t stream) {
  const float* out_pts = (const float*)d_in[0];
  const float* tgt_pts = (const float*)d_in[1];
  float* out = (float*)d_out;

  hipMemsetAsync(out, 0, out_size * sizeof(float), stream);
  if (ws_size >= WS_NEED) {
    float4* ws = (float4*)d_ws;
    prep_kernel<<<(int)(WS_ELEMS / THREADS), THREADS, 0, stream>>>(out_pts, tgt_pts, ws);
    dim3 grid(QTILES, PAIRS, 2);
    chamfer_sgpr_kernel<<<grid, THREADS, 0, stream>>>(out_pts, tgt_pts, ws, out);
  } else {
    dim3 grid(NPTS / THREADS, PAIRS, 2);
    chamfer_lds_kernel<<<grid, THREADS, 0, stream>>>(out_pts, tgt_pts, out);
  }
}

// Round 4
// 128.775 us; speedup vs baseline: 1.0999x; 1.0999x over previous
//
#include <hip/hip_runtime.h>

// Chamfer distance: B=4, S=4, N=M=4096, D=3, fp32 in/out.
// out[s*B + b] = mean_n min_m d2(n,m) + mean_m min_n d2(n,m)
//
// R4: SGPR-streamed refs (s_load_dwordx16), 2 queries/thread.
//  - refs wave-uniform -> scalar pipe, zero DS traffic (R1 was DS-bound).
//  - R3 showed ~38% VALU duty: per-batch lgkmcnt(0) drains expose SMEM
//    latency (~400-500cyc). 2 queries/thread doubles compute per drain
//    (144 cyc own-issue) and halves K$ request rate.
//  - max-form: prep stores w = -0.5*|r|^2; g = q.r + w (3 fma, shared w mov);
//    d2 = max(x2 - 2*max_m g, 0). 9 VALU / (ref,thread) = 4.5 ops/pair.

constexpr int B = 4, S = 4, NPTS = 4096, PAIRS = B * S;
constexpr int THREADS = 256;
constexpr int QPB = 128;                  // queries per block (2 per thread, per wave)
constexpr int QUARTER = NPTS / 4;         // refs per wave (4-way split across waves)
constexpr int QTILES = NPTS / QPB;        // 32
constexpr size_t WS_ELEMS = (size_t)2 * PAIRS * NPTS;          // packed float4 refs
constexpr size_t WS_NEED  = WS_ELEMS * sizeof(float4) + 512;   // +prefetch overshoot pad

typedef float v16f __attribute__((ext_vector_type(16)));

#define SLOAD(dst, p, imm) \
  asm volatile("s_load_dwordx16 %0, %1, %2" : "=s"(dst) : "s"(p), "i"(imm))
#define SWAIT2(a, b) \
  asm volatile("s_waitcnt lgkmcnt(0)" : "+s"(a), "+s"(b))
#define SDRAIN() asm volatile("s_waitcnt lgkmcnt(0)" ::: "memory")

// ---- prep: pack refs as (x, y, z, -0.5*|r|^2), layout [dir][pair][n] ----
__global__ void prep_kernel(const float* __restrict__ out_pts,
                            const float* __restrict__ tgt_pts,
                            float4* __restrict__ ws) {
  int i = blockIdx.x * blockDim.x + threadIdx.x;   // 0 .. 2*16*4096-1
  int dir = i >> 16;                                // 16*4096 = 65536 per dir
  int rem = i & 65535;                              // pair*NPTS + n
  const float* p = (dir == 0 ? tgt_pts : out_pts) + (size_t)rem * 3;
  float x = p[0], y = p[1], z = p[2];
  ws[i] = make_float4(x, y, z, -0.5f * (x * x + y * y + z * z));
}

// ---- main: SGPR-streamed brute-force NN, 2 queries per thread ----
__global__ __launch_bounds__(THREADS, 4)
void chamfer_sgpr2_kernel(const float* __restrict__ out_pts,
                          const float* __restrict__ tgt_pts,
                          const float4* __restrict__ ws,
                          float* __restrict__ out) {
  const int t     = threadIdx.x;
  const int qtile = blockIdx.x;   // 0..31
  const int pair  = blockIdx.y;   // 0..15  (pair = b*S + s)
  const int dir   = blockIdx.z;   // 0: out->tgt, 1: tgt->out
  // Wave-uniform quarter index (laundered so ref pointer stays in SGPRs).
  const int wv    = __builtin_amdgcn_readfirstlane(t) >> 6;   // 0..3

  const float* qbase = (dir == 0 ? out_pts : tgt_pts) + (size_t)pair * NPTS * 3;
  const float4* rbase =
      ws + (size_t)(dir * PAIRS + pair) * NPTS + (size_t)wv * QUARTER;

  const int l  = t & 63;
  const int q0 = qtile * QPB + l;        // queries [qtile*128, +64)
  const int q1 = q0 + 64;                // queries [qtile*128+64, +64)
  const float qx0 = qbase[q0 * 3 + 0], qy0 = qbase[q0 * 3 + 1], qz0 = qbase[q0 * 3 + 2];
  const float qx1 = qbase[q1 * 3 + 0], qy1 = qbase[q1 * 3 + 1], qz1 = qbase[q1 * 3 + 2];

  // 4 independent max chains per query (8 total) -> plenty of ILP.
  float m0[4], m1[4];
  #pragma unroll
  for (int u = 0; u < 4; ++u) { m0[u] = -3.0e38f; m1[u] = -3.0e38f; }

  // Double-buffered SMEM stream: 8 refs (128 B = 2x s_load_dwordx16) / batch.
  // SMEM may complete out of order -> each wait is a full lgkmcnt(0) drain;
  // a batch's loads are issued BEFORE the drain preceding its use.
  v16f a0, a1, b0, b1;
  const float4* p = rbase;
  SLOAD(a0, p, 0);  SLOAD(a1, p, 64);

  #define BODY8(va, vb)                                          \
    { _Pragma("unroll") for (int j = 0; j < 4; ++j) {            \
        float w = (va)[4 * j + 3];                               \
        float g0 = fmaf(qx0, (va)[4 * j], w);                    \
        g0 = fmaf(qy0, (va)[4 * j + 1], g0);                     \
        g0 = fmaf(qz0, (va)[4 * j + 2], g0);                     \
        m0[j] = fmaxf(m0[j], g0);                                \
        float g1 = fmaf(qx1, (va)[4 * j], w);                    \
        g1 = fmaf(qy1, (va)[4 * j + 1], g1);                     \
        g1 = fmaf(qz1, (va)[4 * j + 2], g1);                     \
        m1[j] = fmaxf(m1[j], g1); }                              \
      _Pragma("unroll") for (int j = 0; j < 4; ++j) {            \
        float w = (vb)[4 * j + 3];                               \
        float g0 = fmaf(qx0, (vb)[4 * j], w);                    \
        g0 = fmaf(qy0, (vb)[4 * j + 1], g0);                     \
        g0 = fmaf(qz0, (vb)[4 * j + 2], g0);                     \
        m0[j] = fmaxf(m0[j], g0);                                \
        float g1 = fmaf(qx1, (vb)[4 * j], w);                    \
        g1 = fmaf(qy1, (vb)[4 * j + 1], g1);                     \
        g1 = fmaf(qz1, (vb)[4 * j + 2], g1);                     \
        m1[j] = fmaxf(m1[j], g1); } }

  for (int k = 0; k < QUARTER; k += 16) {
    SWAIT2(a0, a1);
    SLOAD(b0, p, 128); SLOAD(b1, p, 192);   // batch k+8 in flight
    BODY8(a0, a1);                          // batch k
    SWAIT2(b0, b1);
    SLOAD(a0, p, 256); SLOAD(a1, p, 320);   // batch k+16 (overshoots <=384 B
    BODY8(b0, b1);                          //  past stream end; ws is padded)
    p += 16;
  }
  #undef BODY8
  SDRAIN();   // loop exits with 2 loads in flight; drain before regs get reused

  float t0 = fmaxf(fmaxf(m0[0], m0[1]), fmaxf(m0[2], m0[3]));
  float t1 = fmaxf(fmaxf(m1[0], m1[1]), fmaxf(m1[2], m1[3]));
  const float x20 = qx0 * qx0 + qy0 * qy0 + qz0 * qz0;
  const float x21 = qx1 * qx1 + qy1 * qy1 + qz1 * qz1;

  // Combine the 4 wave-partials per query, then block-sum.
  __shared__ float pm[4 * QPB];
  __shared__ float red[2];
  pm[wv * QPB + l] = t0;
  pm[wv * QPB + 64 + l] = t1;
  __syncthreads();
  if (t < QPB) {
    // thread t finalizes block-query t: wave0 t<64 -> its q0; wave1 -> its q1.
    float g = fmaxf(fmaxf(pm[t], pm[QPB + t]),
                    fmaxf(pm[2 * QPB + t], pm[3 * QPB + t]));
    float x2 = (t < 64) ? x20 : x21;
    float d = fmaxf(fmaf(-2.0f, g, x2), 0.0f);   // min squared distance
    #pragma unroll
    for (int off = 1; off < 64; off <<= 1) d += __shfl_xor(d, off, 64);
    if ((t & 63) == 0) red[t >> 6] = d;
  }
  __syncthreads();
  if (t == 0) {
    float ssum = red[0] + red[1];
    int b = pair >> 2, s = pair & 3;        // pair = b*S + s, S = 4
    atomicAdd(&out[s * B + b], ssum * (1.0f / NPTS));
  }
}

// ---- R1 fallback (LDS broadcast) in case d_ws is too small ----
constexpr int FB_CHUNK = 2048;
__global__ __launch_bounds__(THREADS, 2)
void chamfer_lds_kernel(const float* __restrict__ out_pts,
                        const float* __restrict__ tgt_pts,
                        float* __restrict__ out) {
  const int t = threadIdx.x, qtile = blockIdx.x, pair = blockIdx.y, dir = blockIdx.z;
  const float* qbase = (dir == 0 ? out_pts : tgt_pts) + (size_t)pair * NPTS * 3;
  const float* rbase = (dir == 0 ? tgt_pts : out_pts) + (size_t)pair * NPTS * 3;
  __shared__ float4 sref[FB_CHUNK];
  const int q = qtile * THREADS + t;
  const float qx = qbase[q * 3], qy = qbase[q * 3 + 1], qz = qbase[q * 3 + 2];
  float mm[8];
  #pragma unroll
  for (int u = 0; u < 8; ++u) mm[u] = 3.0e38f;
  for (int c0 = 0; c0 < NPTS; c0 += FB_CHUNK) {
    if (c0) __syncthreads();
    for (int i = t; i < FB_CHUNK; i += THREADS) {
      const float* p = rbase + (size_t)(c0 + i) * 3;
      float rx = p[0], ry = p[1], rz = p[2];
      sref[i] = make_float4(rx, ry, rz, 0.5f * (rx * rx + ry * ry + rz * rz));
    }
    __syncthreads();
    for (int k = 0; k < FB_CHUNK; k += 8) {
      #pragma unroll
      for (int u = 0; u < 8; ++u) {
        float4 r = sref[k + u];
        float a = fmaf(-qx, r.x, r.w);
        a = fmaf(-qy, r.y, a);
        a = fmaf(-qz, r.z, a);
        mm[u] = fminf(mm[u], a);
      }
    }
  }
  float tmin = fminf(fminf(fminf(mm[0], mm[1]), fminf(mm[2], mm[3])),
                     fminf(fminf(mm[4], mm[5]), fminf(mm[6], mm[7])));
  float x2 = qx * qx + qy * qy + qz * qz;
  float d = fmaxf(fmaf(2.0f, tmin, x2), 0.0f);
  #pragma unroll
  for (int off = 1; off < 64; off <<= 1) d += __shfl_xor(d, off, 64);
  __syncthreads();
  float* red = reinterpret_cast<float*>(sref);
  if ((t & 63) == 0) red[t >> 6] = d;
  __syncthreads();
  if (t == 0) {
    float ssum = red[0] + red[1] + red[2] + red[3];
    int b = pair >> 2, s = pair & 3;
    atomicAdd(&out[s * B + b], ssum * (1.0f / NPTS));
  }
}

extern "C" void kernel_launch(void* const* d_in, const int* in_sizes, int n_in,
                              void* d_out, int out_size, void* d_ws, size_t ws_size,
                              hipStream_t stream) {
  const float* out_pts = (const float*)d_in[0];
  const float* tgt_pts = (const float*)d_in[1];
  float* out = (float*)d_out;

  hipMemsetAsync(out, 0, out_size * sizeof(float), stream);
  if (ws_size >= WS_NEED) {
    float4* ws = (float4*)d_ws;
    prep_kernel<<<(int)(WS_ELEMS / THREADS), THREADS, 0, stream>>>(out_pts, tgt_pts, ws);
    dim3 grid(QTILES, PAIRS, 2);
    chamfer_sgpr2_kernel<<<grid, THREADS, 0, stream>>>(out_pts, tgt_pts, ws, out);
  } else {
    dim3 grid(NPTS / THREADS, PAIRS, 2);
    chamfer_lds_kernel<<<grid, THREADS, 0, stream>>>(out_pts, tgt_pts, out);
  }
}

// Round 5
// 103.717 us; speedup vs baseline: 1.3656x; 1.2416x over previous
//
#include <hip/hip_runtime.h>

// Chamfer distance: B=4, S=4, N=M=4096, D=3, fp32 in/out.
// out[s*B + b] = mean_n min_m d2(n,m) + mean_m min_n d2(n,m)
//
// R5: LDS-broadcast refs + 8 queries/thread.
//  - R1 was DS-writeback bound (~6.7 cyc per broadcast ds_read_b128, measured);
//    packing Q=8 queries/thread amortizes each ref read over 8 pairs:
//    DS = 1.05M wave-reads * 8cyc / 256 CU = 13.7 us.
//  - R3/R4 SGPR streaming is Little's-law capped (~2 x16 loads in flight/wave,
//    SGPR budget 102/wave) at ~40+ us -> abandoned.
//  - refs arrive in VGPRs -> g = fmaf(qz,rz,w); fmaf; fmaf; max = exactly
//    4 VALU/pair (w is the fma addend, no v_mov). VALU floor = 27.3 us.
//  - max-form: w = -0.5*|r|^2; min d2 = max(x2 - 2*max_m g, 0).
// One block per (qtile,pair,dir): 512 thr (8 waves), all 4096 refs staged to
// 64KB LDS once; wave w computes ref segment [w*512, w*512+512); partial
// maxima combined through LDS (reused as scratch after a barrier).

constexpr int B = 4, S = 4, NPTS = 4096, PAIRS = B * S;
constexpr int THREADS = 512;            // 8 waves
constexpr int QPT = 8;                  // queries per thread
constexpr int QPB = 64 * QPT;           // 512 queries per block
constexpr int QTILES = NPTS / QPB;      // 8
constexpr int SEG = NPTS / 8;           // refs per wave

__global__ __launch_bounds__(THREADS, 2)
void chamfer_q8_kernel(const float* __restrict__ out_pts,
                       const float* __restrict__ tgt_pts,
                       float* __restrict__ out) {
  const int t     = threadIdx.x;
  const int l     = t & 63;
  const int wid   = t >> 6;        // 0..7
  const int qtile = blockIdx.x;    // 0..7
  const int pair  = blockIdx.y;    // 0..15 (pair = b*S + s)
  const int dir   = blockIdx.z;    // 0: out->tgt, 1: tgt->out

  const float* qbase = (dir == 0 ? out_pts : tgt_pts) + (size_t)pair * NPTS * 3;
  const float* rbase = (dir == 0 ? tgt_pts : out_pts) + (size_t)pair * NPTS * 3;

  __shared__ float4 sref[NPTS];    // 64 KB; scratch-reused after compute

  // ---- stage all 4096 refs as (x,y,z,-0.5*|r|^2).
  // ref index = t + k*512: consecutive lanes -> consecutive float4s in LDS
  // (conflict-free ds_write_b128 pattern).
  #pragma unroll
  for (int k = 0; k < 8; ++k) {
    const int i = t + k * THREADS;
    const float rx = rbase[3 * i], ry = rbase[3 * i + 1], rz = rbase[3 * i + 2];
    sref[i] = make_float4(rx, ry, rz, -0.5f * (rx * rx + ry * ry + rz * rz));
  }

  // ---- load this thread's 8 queries (same across all 8 waves).
  float qx[QPT], qy[QPT], qz[QPT];
  #pragma unroll
  for (int j = 0; j < QPT; ++j) {
    const int q = qtile * QPB + j * 64 + l;
    qx[j] = qbase[3 * q];
    qy[j] = qbase[3 * q + 1];
    qz[j] = qbase[3 * q + 2];
  }

  float acc[QPT];
  #pragma unroll
  for (int j = 0; j < QPT; ++j) acc[j] = -3.0e38f;

  __syncthreads();

  // ---- hot loop: wave-broadcast ds_read_b128, 32 VALU per ref (8 pairs).
  const int base = wid * SEG;
  #pragma unroll 4
  for (int r = 0; r < SEG; ++r) {
    const float4 rf = sref[base + r];
    #pragma unroll
    for (int j = 0; j < QPT; ++j) {
      float g = fmaf(qz[j], rf.z, rf.w);
      g = fmaf(qy[j], rf.y, g);
      g = fmaf(qx[j], rf.x, g);
      acc[j] = fmaxf(acc[j], g);
    }
  }

  __syncthreads();                 // everyone done reading sref
  float* Sf = reinterpret_cast<float*>(sref);

  // part[wid][qidx] and (wave 0) x2 stash; lane-consecutive addresses.
  #pragma unroll
  for (int j = 0; j < QPT; ++j) Sf[wid * QPB + j * 64 + l] = acc[j];
  if (wid == 0) {
    #pragma unroll
    for (int j = 0; j < QPT; ++j)
      Sf[8 * QPB + j * 64 + l] =
          qx[j] * qx[j] + qy[j] * qy[j] + qz[j] * qz[j];
  }
  __syncthreads();

  // thread t finalizes block-query t (THREADS == QPB == 512).
  float g = Sf[t];
  #pragma unroll
  for (int w = 1; w < 8; ++w) g = fmaxf(g, Sf[w * QPB + t]);
  float d = fmaxf(fmaf(-2.0f, g, Sf[8 * QPB + t]), 0.0f);  // min sq dist

  #pragma unroll
  for (int off = 1; off < 64; off <<= 1) d += __shfl_xor(d, off, 64);
  __syncthreads();
  if (l == 0) Sf[9 * QPB + wid] = d;
  __syncthreads();
  if (t == 0) {
    float ssum = 0.0f;
    #pragma unroll
    for (int w = 0; w < 8; ++w) ssum += Sf[9 * QPB + w];
    const int b = pair >> 2, s = pair & 3;   // pair = b*S + s, S = 4
    atomicAdd(&out[s * B + b], ssum * (1.0f / NPTS));
  }
}

extern "C" void kernel_launch(void* const* d_in, const int* in_sizes, int n_in,
                              void* d_out, int out_size, void* d_ws, size_t ws_size,
                              hipStream_t stream) {
  const float* out_pts = (const float*)d_in[0];
  const float* tgt_pts = (const float*)d_in[1];
  float* out = (float*)d_out;

  hipMemsetAsync(out, 0, out_size * sizeof(float), stream);
  dim3 grid(QTILES, PAIRS, 2);     // 256 blocks, 1 per CU
  chamfer_q8_kernel<<<grid, THREADS, 0, stream>>>(out_pts, tgt_pts, out);
}

// Round 7
// 98.210 us; speedup vs baseline: 1.4422x; 1.0561x over previous
//
#include <hip/hip_runtime.h>

// Chamfer distance: B=4, S=4, N=M=4096, D=3, fp32 in/out.
// out[s*B + b] = mean_n min_m d2(n,m) + mean_m min_n d2(n,m)
//
// R7: LDS-broadcast refs + 8 queries/thread, packed fp32 FMA + max3 merge.
//  - gfx950 HAS v_pk_fma_f32 (VOP3P, op_sel broadcasts the wave-uniform ref
//    scalars straight from the float4 reg pairs) but NO v_pk_max_f32 (R6
//    compile error). Max is done scalar via v_max3_f32, merging TWO refs per
//    accumulator update: per ref-pair per packed query-pair:
//    6 pk_fma + 2 max3 -> 16 insts per ref per thread (8 queries) = 2/pair.
//  - 1024-thr blocks (16 waves, 4 waves/SIMD, 1 block/CU): R5 showed
//    ~4cyc/inst effective at 2 waves/SIMD (issue-starved).
//  - max-form: w = -0.5*|r|^2; g = q.r + w; min d2 = max(x2 - 2*max_m g, 0).
// VALU floor 13.7 us, DS-pipe 13.7 us (overlapped).

constexpr int B = 4, S = 4, NPTS = 4096, PAIRS = B * S;
constexpr int THREADS = 1024;           // 16 waves
constexpr int WAVES = THREADS / 64;
constexpr int QPT = 8;                  // queries per thread (4 packed pairs)
constexpr int QPB = 64 * QPT;           // 512 queries per block
constexpr int QTILES = NPTS / QPB;      // 8
constexpr int SEG = NPTS / WAVES;       // 256 refs per wave

typedef float v2f __attribute__((ext_vector_type(2)));

// g = (q.lo*rz + w, q.hi*rz + w)   [rzw = (rz, w): src1 bcast lo, src2 bcast hi]
#define PK_FMA_ZW(g, q, rzw)                                              \
  asm("v_pk_fma_f32 %0, %1, %2, %2 op_sel:[0,0,1] op_sel_hi:[1,0,1]"      \
      : "=v"(g) : "v"(q), "v"(rzw))
// g += q*ry                        [rxy = (rx, ry): src1 bcast hi]
#define PK_FMA_Y(g, q, rxy)                                               \
  asm("v_pk_fma_f32 %0, %1, %2, %0 op_sel:[0,1,0] op_sel_hi:[1,1,1]"      \
      : "+v"(g) : "v"(q), "v"(rxy))
// g += q*rx                        [src1 bcast lo]
#define PK_FMA_X(g, q, rxy)                                               \
  asm("v_pk_fma_f32 %0, %1, %2, %0 op_sel:[0,0,0] op_sel_hi:[1,0,1]"      \
      : "+v"(g) : "v"(q), "v"(rxy))

__global__ __launch_bounds__(THREADS, 4)
void chamfer_pk3_kernel(const float* __restrict__ out_pts,
                        const float* __restrict__ tgt_pts,
                        float* __restrict__ out) {
  const int t     = threadIdx.x;
  const int l     = t & 63;
  const int wid   = t >> 6;        // 0..15
  const int qtile = blockIdx.x;    // 0..7
  const int pair  = blockIdx.y;    // 0..15 (pair = b*S + s)
  const int dir   = blockIdx.z;    // 0: out->tgt, 1: tgt->out

  const float* qbase = (dir == 0 ? out_pts : tgt_pts) + (size_t)pair * NPTS * 3;
  const float* rbase = (dir == 0 ? tgt_pts : out_pts) + (size_t)pair * NPTS * 3;

  __shared__ float4 sref[NPTS];    // 64 KB; scratch-reused after compute

  // ---- stage all 4096 refs as (x,y,z,-0.5*|r|^2); lane-consecutive writes.
  #pragma unroll
  for (int k = 0; k < NPTS / THREADS; ++k) {
    const int i = t + k * THREADS;
    const float rx = rbase[3 * i], ry = rbase[3 * i + 1], rz = rbase[3 * i + 2];
    sref[i] = make_float4(rx, ry, rz, -0.5f * (rx * rx + ry * ry + rz * rz));
  }

  // ---- 8 queries/thread as 4 packed (lo,hi) pairs; same across all waves.
  v2f qx[4], qy[4], qz[4];
  #pragma unroll
  for (int p = 0; p < 4; ++p) {
    const int q0 = qtile * QPB + (2 * p) * 64 + l;
    const int q1 = q0 + 64;
    qx[p] = v2f{qbase[3 * q0], qbase[3 * q1]};
    qy[p] = v2f{qbase[3 * q0 + 1], qbase[3 * q1 + 1]};
    qz[p] = v2f{qbase[3 * q0 + 2], qbase[3 * q1 + 2]};
  }

  float acc[QPT];
  #pragma unroll
  for (int j = 0; j < QPT; ++j) acc[j] = -3.0e38f;

  __syncthreads();

  // ---- hot loop: 2 refs/iter; 2 broadcast ds_read_b128 + 32 VALU (8 q).
  const int base = wid * SEG;
  #pragma unroll 2
  for (int r = 0; r < SEG; r += 2) {
    const float4 rf0 = sref[base + r];
    const float4 rf1 = sref[base + r + 1];
    v2f rxy0; rxy0.x = rf0.x; rxy0.y = rf0.y;
    v2f rzw0; rzw0.x = rf0.z; rzw0.y = rf0.w;
    v2f rxy1; rxy1.x = rf1.x; rxy1.y = rf1.y;
    v2f rzw1; rzw1.x = rf1.z; rzw1.y = rf1.w;
    #pragma unroll
    for (int p = 0; p < 4; ++p) {
      v2f g0, g1;
      PK_FMA_ZW(g0, qz[p], rzw0);
      PK_FMA_Y (g0, qy[p], rxy0);
      PK_FMA_X (g0, qx[p], rxy0);
      PK_FMA_ZW(g1, qz[p], rzw1);
      PK_FMA_Y (g1, qy[p], rxy1);
      PK_FMA_X (g1, qx[p], rxy1);
      acc[2 * p]     = fmaxf(fmaxf(acc[2 * p], g0.x), g1.x);      // v_max3
      acc[2 * p + 1] = fmaxf(fmaxf(acc[2 * p + 1], g0.y), g1.y);  // v_max3
    }
  }

  __syncthreads();                 // all waves done reading sref
  float* Sf = reinterpret_cast<float*>(sref);

  // partials: Sf[wid*512 + qidx], lane-consecutive (stride-1, conflict-free)
  #pragma unroll
  for (int j = 0; j < QPT; ++j) Sf[wid * QPB + j * 64 + l] = acc[j];
  __syncthreads();

  // threads 0..511 finalize one block-query each (waves 0..7).
  if (t < QPB) {
    float g = Sf[t];
    #pragma unroll
    for (int w = 1; w < WAVES; ++w) g = fmaxf(g, Sf[w * QPB + t]);
    const int j = t >> 6, p = j >> 1, h = j & 1;   // this thread loaded query t
    const float x2 = qx[p][h] * qx[p][h] + qy[p][h] * qy[p][h] + qz[p][h] * qz[p][h];
    float d = fmaxf(fmaf(-2.0f, g, x2), 0.0f);     // min squared distance
    #pragma unroll
    for (int off = 1; off < 64; off <<= 1) d += __shfl_xor(d, off, 64);
    if (l == 0) Sf[WAVES * QPB + (t >> 6)] = d;
  }
  __syncthreads();
  if (t == 0) {
    float ssum = 0.0f;
    #pragma unroll
    for (int w = 0; w < QPB / 64; ++w) ssum += Sf[WAVES * QPB + w];
    const int b = pair >> 2, s = pair & 3;   // pair = b*S + s, S = 4
    atomicAdd(&out[s * B + b], ssum * (1.0f / NPTS));
  }
}

extern "C" void kernel_launch(void* const* d_in, const int* in_sizes, int n_in,
                              void* d_out, int out_size, void* d_ws, size_t ws_size,
                              hipStream_t stream) {
  const float* out_pts = (const float*)d_in[0];
  const float* tgt_pts = (const float*)d_in[1];
  float* out = (float*)d_out;

  hipMemsetAsync(out, 0, out_size * sizeof(float), stream);
  dim3 grid(QTILES, PAIRS, 2);     // 256 blocks, 1 per CU
  chamfer_pk3_kernel<<<grid, THREADS, 0, stream>>>(out_pts, tgt_pts, out);
}